// Round 1
// baseline (363.844 us; speedup 1.0000x reference)
//
#include <hip/hip_runtime.h>

// spectral_blurrin: x [1, 256, 512, 512] fp32 -> out [1, 64, 512, 512] fp32
// out[oc, h, w] = mean over f in [0,4) of x[4*oc + f, h, w]
//
// Pure streaming kernel: 256 MiB read + 64 MiB write, no reuse.
// Roofline at 6.3 TB/s achievable HBM BW: ~53 us.

constexpr int HW   = 512 * 512;   // elements per channel plane
constexpr int HW4  = HW / 4;      // float4 per plane = 65536 (pow2)
constexpr int OC   = 64;          // output channels = 256 / 4
constexpr int NOUT4 = OC * HW4;   // total float4 outputs = 4,194,304

__global__ __launch_bounds__(256)
void spectral_blurrin_kernel(const float4* __restrict__ x,
                             float4* __restrict__ out) {
    const int i = blockIdx.x * blockDim.x + threadIdx.x;  // [0, NOUT4)
    const int oc = i >> 16;          // i / HW4   (HW4 == 65536)
    const int p  = i & (HW4 - 1);    // i % HW4

    const float4* base = x + ((size_t)oc * 4) * (size_t)HW4 + (size_t)p;
    const float4 a = base[0];
    const float4 b = base[HW4];
    const float4 c = base[2 * HW4];
    const float4 d = base[3 * HW4];

    float4 r;
    r.x = ((a.x + b.x) + (c.x + d.x)) * 0.25f;
    r.y = ((a.y + b.y) + (c.y + d.y)) * 0.25f;
    r.z = ((a.z + b.z) + (c.z + d.z)) * 0.25f;
    r.w = ((a.w + b.w) + (c.w + d.w)) * 0.25f;

    out[i] = r;
}

extern "C" void kernel_launch(void* const* d_in, const int* in_sizes, int n_in,
                              void* d_out, int out_size, void* d_ws, size_t ws_size,
                              hipStream_t stream) {
    const float4* x  = (const float4*)d_in[0];
    float4* out      = (float4*)d_out;
    // factor (d_in[1]) is a fixed scalar 4 per setup_inputs; shapes hardcoded.

    const int threads = 256;
    const int blocks  = NOUT4 / threads;  // 16384
    spectral_blurrin_kernel<<<blocks, threads, 0, stream>>>(x, out);
}

// Round 2
// 354.372 us; speedup vs baseline: 1.0267x; 1.0267x over previous
//
#include <hip/hip_runtime.h>

// spectral_blurrin: x [1, 256, 512, 512] fp32 -> out [1, 64, 512, 512] fp32
// out[oc, h, w] = mean over f in [0,4) of x[4*oc + f, h, w]
//
// Streaming reduction: 256 MiB read + 64 MiB write, zero reuse.
// Roofline at ~6.5 TB/s (measured via harness fills): ~52 us kernel time.
//
// R2 changes vs R1:
//  - 4 float4 outputs per thread -> 16 independent loads in flight (MLP),
//    16 KiB contiguous per input stream per block (DRAM page locality).
//  - nontemporal loads/stores: zero reuse, don't thrash 32 MiB L2.

typedef float f4 __attribute__((ext_vector_type(4)));

constexpr int HW4   = 512 * 512 / 4;  // float4 per plane = 65536 (pow2)
constexpr int OC    = 64;             // output channels
constexpr int TPB   = 256;            // threads per block
constexpr int VPT   = 4;              // float4 outputs per thread
constexpr int CHUNK = TPB * VPT;      // 1024 float4 per block
constexpr int BLOCKS_PER_OC = HW4 / CHUNK;  // 64
constexpr int NBLOCKS = OC * BLOCKS_PER_OC; // 4096

__global__ __launch_bounds__(TPB)
void spectral_blurrin_kernel(const f4* __restrict__ x,
                             f4* __restrict__ out) {
    const int b     = blockIdx.x;
    const int oc    = b >> 6;                       // b / BLOCKS_PER_OC
    const int pbase = ((b & (BLOCKS_PER_OC - 1)) * CHUNK) + (int)threadIdx.x;

    const f4* __restrict__ xp = x + ((size_t)(oc * 4)) * HW4 + pbase;
    f4* __restrict__       op = out + (size_t)oc * HW4 + pbase;

    f4 v[VPT];
#pragma unroll
    for (int j = 0; j < VPT; ++j) {
        const f4* q = xp + j * TPB;
        f4 a = __builtin_nontemporal_load(q);
        f4 bb = __builtin_nontemporal_load(q + HW4);
        f4 c = __builtin_nontemporal_load(q + 2 * HW4);
        f4 d = __builtin_nontemporal_load(q + 3 * HW4);
        v[j] = ((a + bb) + (c + d)) * 0.25f;
    }
#pragma unroll
    for (int j = 0; j < VPT; ++j) {
        __builtin_nontemporal_store(v[j], op + j * TPB);
    }
}

extern "C" void kernel_launch(void* const* d_in, const int* in_sizes, int n_in,
                              void* d_out, int out_size, void* d_ws, size_t ws_size,
                              hipStream_t stream) {
    const f4* x = (const f4*)d_in[0];
    f4* out     = (f4*)d_out;
    spectral_blurrin_kernel<<<NBLOCKS, TPB, 0, stream>>>(x, out);
}